// Round 11
// baseline (125.962 us; speedup 1.0000x reference)
//
#include <hip/hip_runtime.h>
#include <hip/hip_bf16.h>
#include <math.h>

// Problem constants (from reference setup_inputs)
#define BB 32
#define DD 64
#define HH 32
#define WW 32
#define NN (BB * HH * WW)       // 32768 rows
#define KK 1024                 // codes
#define HW (HH * WW)            // 1024
#define NQ (BB * DD * HH * WW)  // 2097152 quantized elements
#define NBLK 512                // k_main grid (64 rows/block) -> 2 blocks/CU

#define EPS_F 1e-12f
#define PERP_EPS_F 1e-10f
#define DIST_BIAS 512.0f        // makes dist strictly positive -> uint-monotonic

typedef __attribute__((ext_vector_type(8))) __bf16 bf16x8;
typedef __attribute__((ext_vector_type(8))) unsigned short u16x8;
typedef __attribute__((ext_vector_type(4))) float f32x4;

// fp32 -> bf16 round-to-nearest-even, bit-level
static __device__ __forceinline__ unsigned short f2bf(float f) {
    union { float f; unsigned int u; } c;
    c.f = f;
    unsigned int r = c.u + 0x7FFFu + ((c.u >> 16) & 1u);
    return (unsigned short)(r >> 16);
}

// ---------------------------------------------------------------------------
// Kernel 1: codes fp32 -> bf16 pre-swizzled into MFMA B-frag order + norms +
// zero histogram. Swizzled layout: tile jt (16 codes), k-half f, MFMA lane
// l=(quad*16+col): element e at
//   cbs[((jt*2+f)*64 + l)*8 + e] == code[jt*16+col][f*32 + quad*8 + e]
// so the K-loop B-load is base + jt*2048B + lane*16B (fully coalesced).
// ---------------------------------------------------------------------------
__global__ __launch_bounds__(256) void k_prep(const float* __restrict__ cb,
                                              unsigned short* __restrict__ cbs,
                                              float* __restrict__ cnorm,
                                              unsigned int* __restrict__ counts) {
    const int gt = blockIdx.x * 256 + threadIdx.x;  // 0..4095
    const int j = gt >> 2;   // code 0..1023
    const int q = gt & 3;    // d-quarter 0..3
    const int jt = j >> 4;
    const int col = j & 15;
    const float4* src = reinterpret_cast<const float4*>(cb + (size_t)j * DD + q * 16);
    float4 v0 = src[0], v1 = src[1], v2 = src[2], v3 = src[3];
    float s = v0.x * v0.x + v0.y * v0.y + v0.z * v0.z + v0.w * v0.w
            + v1.x * v1.x + v1.y * v1.y + v1.z * v1.z + v1.w * v1.w
            + v2.x * v2.x + v2.y * v2.y + v2.z * v2.z + v2.w * v2.w
            + v3.x * v3.x + v3.y * v3.y + v3.z * v3.z + v3.w * v3.w;

#pragma unroll
    for (int i2 = 0; i2 < 2; ++i2) {
        const int quad_lin = q * 2 + i2;     // 0..7
        const int frag = quad_lin >> 2;      // k-half
        const int quad = quad_lin & 3;
        const int lane = quad * 16 + col;
        u16x8 pk;
        if (i2 == 0) {
            pk[0] = f2bf(v0.x); pk[1] = f2bf(v0.y); pk[2] = f2bf(v0.z); pk[3] = f2bf(v0.w);
            pk[4] = f2bf(v1.x); pk[5] = f2bf(v1.y); pk[6] = f2bf(v1.z); pk[7] = f2bf(v1.w);
        } else {
            pk[0] = f2bf(v2.x); pk[1] = f2bf(v2.y); pk[2] = f2bf(v2.z); pk[3] = f2bf(v2.w);
            pk[4] = f2bf(v3.x); pk[5] = f2bf(v3.y); pk[6] = f2bf(v3.z); pk[7] = f2bf(v3.w);
        }
        *reinterpret_cast<u16x8*>(cbs + ((size_t)(jt * 2 + frag) * 64 + lane) * 8) = pk;
    }

    s += __shfl_xor(s, 1);
    s += __shfl_xor(s, 2);
    if (q == 0) {
        cnorm[j] = s + DIST_BIAS;
        counts[j] = 0u;
    }
}

// ---------------------------------------------------------------------------
// Kernel 2 (fused): 512 blocks x 512 threads (8 waves), 64 rows/block.
// *** INSTRUMENTATION BUILD: the argmin K-loop runs TWICE (idempotent min,
// result bit-identical) to push k_main above the rocprof top-5 cutoff and
// measure K-loop time = dur(R11) - dur(R10). ***
// ---------------------------------------------------------------------------
__global__ __launch_bounds__(512) void k_main(const float* __restrict__ inp,
                                              const unsigned short* __restrict__ cbs,
                                              const float* __restrict__ cb,
                                              const float* __restrict__ cnorm,
                                              const float* __restrict__ noise,
                                              unsigned int* __restrict__ counts,
                                              float* __restrict__ out) {
    __shared__ float xs[64 * 65];                          // fp32 x, [d][r] stride 65
    __shared__ __align__(16) unsigned short scratch[64 * 72];  // A-tile; later bf16 noise [r][d]@65
    __shared__ unsigned int mg[64 * 4];                    // winner per [row][quarter]
    __shared__ int jwin[64];
    __shared__ float sscale[64];

    unsigned short* xls = scratch;            // bf16 A-tile [r][d], stride 72
    unsigned short* nsu = scratch;            // later: bf16 noise [r][d], stride 65

    const int tid = threadIdx.x;
    const int nbase = blockIdx.x * 64;
    const int b = nbase >> 10;        // 64 | 1024: no batch/HW crossing
    const int hwbase = nbase & 1023;
    const float* xg = inp + (size_t)b * (DD * HW) + hwbase;

    const int lane = tid & 63;
    const int wid = tid >> 6;      // 0..7
    const int w = wid & 3;         // code quarter
    const int rh = wid >> 2;       // row half
    const int rbase = rh * 32;
    const int col = lane & 15;
    const int quad = lane >> 4;

    // Stage x fp32: global [d][hw] -> coalesced (256B segments); LDS stride 65.
#pragma unroll
    for (int i = 0; i < 8; ++i) {
        int idx = i * 512 + tid;  // = d*64 + r
        int d = idx >> 6, r = idx & 63;
        xs[d * 65 + r] = xg[d * HW + r];
    }
    __syncthreads();

    // Build bf16 A-tile [r][d]: thread -> (row rr=tid>>3, octet sg=tid&7).
    {
        const int rr = tid >> 3;    // 0..63
        const int sg = tid & 7;     // 8 dims each
        u16x8 pk;
#pragma unroll
        for (int j2 = 0; j2 < 8; ++j2)
            pk[j2] = f2bf(xs[(sg * 8 + j2) * 65 + rr]);
        *reinterpret_cast<u16x8*>(&xls[rr * 72 + sg * 8]) = pk;
    }
    __syncthreads();

    // A fragments: A[m=lane&15][k=quad*8+j]; 2 row-tiles x 2 k-halves.
    const bf16x8 a00 = *reinterpret_cast<const bf16x8*>(&xls[(rbase + col) * 72 + quad * 8]);
    const bf16x8 a01 = *reinterpret_cast<const bf16x8*>(&xls[(rbase + col) * 72 + 32 + quad * 8]);
    const bf16x8 a10 = *reinterpret_cast<const bf16x8*>(&xls[(rbase + 16 + col) * 72 + quad * 8]);
    const bf16x8 a11 = *reinterpret_cast<const bf16x8*>(&xls[(rbase + 16 + col) * 72 + 32 + quad * 8]);

    unsigned int minu[8];
#pragma unroll
    for (int s = 0; s < 8; ++s) minu[s] = 0xFFFFFFFFu;

    // Swizzled B base for this wave's quarter: tile jt at + jt*1024 elems,
    // lane's 16B at + lane*8; k-half 1 at +512. Fully coalesced.
    const unsigned short* bp = cbs + (size_t)w * 16 * 1024 + lane * 8;
    const float* cnp = cnorm + w * 256 + col;

    // ==== K-loop, run twice (idempotent; memory clobber prevents CSE) ====
    for (int rep = 0; rep < 2; ++rep) {
        __asm__ __volatile__("" ::: "memory");  // forbid cross-rep load CSE

        // Software pipeline: preload groups 0 and 1 (2 tiles each).
        bf16x8 bb[2][4];
#pragma unroll
        for (int pg = 0; pg < 2; ++pg) {
#pragma unroll
            for (int t2 = 0; t2 < 2; ++t2) {
                const size_t off = (size_t)(pg * 2 + t2) * 1024;
                bb[pg][t2 * 2]     = *reinterpret_cast<const bf16x8*>(bp + off);
                bb[pg][t2 * 2 + 1] = *reinterpret_cast<const bf16x8*>(bp + off + 512);
            }
        }

#pragma unroll
        for (int g = 0; g < 8; ++g) {
            const int cb_ = g & 1;
#pragma unroll
            for (int t2 = 0; t2 < 2; ++t2) {
                const int jt = g * 2 + t2;
                f32x4 acc0 = {0.f, 0.f, 0.f, 0.f};
                f32x4 acc1 = {0.f, 0.f, 0.f, 0.f};
                acc0 = __builtin_amdgcn_mfma_f32_16x16x32_bf16(a00, bb[cb_][t2 * 2], acc0, 0, 0, 0);
                acc0 = __builtin_amdgcn_mfma_f32_16x16x32_bf16(a01, bb[cb_][t2 * 2 + 1], acc0, 0, 0, 0);
                acc1 = __builtin_amdgcn_mfma_f32_16x16x32_bf16(a10, bb[cb_][t2 * 2], acc1, 0, 0, 0);
                acc1 = __builtin_amdgcn_mfma_f32_16x16x32_bf16(a11, bb[cb_][t2 * 2 + 1], acc1, 0, 0, 0);
                const float cnt = cnp[jt * 16];
                const unsigned int jc = (unsigned int)(jt * 16 + col);  // 8-bit local idx
#pragma unroll
                for (int r = 0; r < 4; ++r) {
                    float d0 = fmaf(-2.0f, acc0[r], cnt);
                    unsigned int u0 = (__float_as_uint(d0) & ~255u) | jc;
                    minu[r] = minu[r] < u0 ? minu[r] : u0;
                    float d1 = fmaf(-2.0f, acc1[r], cnt);
                    unsigned int u1 = (__float_as_uint(d1) & ~255u) | jc;
                    minu[4 + r] = minu[4 + r] < u1 ? minu[4 + r] : u1;
                }
            }
            // Prefetch group g+2 into the buffer just consumed.
            if (g < 6) {
#pragma unroll
                for (int t2 = 0; t2 < 2; ++t2) {
                    const size_t off = (size_t)((g + 2) * 2 + t2) * 1024;
                    bb[cb_][t2 * 2]     = *reinterpret_cast<const bf16x8*>(bp + off);
                    bb[cb_][t2 * 2 + 1] = *reinterpret_cast<const bf16x8*>(bp + off + 512);
                }
            }
        }
    }

    // 16-col butterfly per quad; index rides in the low bits -> lowest-index tie.
#pragma unroll
    for (int s = 0; s < 8; ++s) {
        unsigned int v = minu[s];
#pragma unroll
        for (int off = 1; off < 16; off <<= 1) {
            unsigned int ov = (unsigned int)__shfl_xor((int)v, off);
            v = v < ov ? v : ov;
        }
        if (col == 0) {
            const int rloc = rbase + (s >> 2) * 16 + quad * 4 + (s & 3);
            mg[rloc * 4 + w] = v;
        }
    }
    __syncthreads();

    // Merge the 4 code-quarters per row; strict '<' keeps lowest quarter on tie.
    if (tid < 64) {
        unsigned int best = mg[tid * 4 + 0];
        unsigned int bestd = best & ~255u;
        int j = (int)(best & 255u);
#pragma unroll
        for (int q = 1; q < 4; ++q) {
            unsigned int uq = mg[tid * 4 + q];
            unsigned int dq = uq & ~255u;
            if (dq < bestd) { bestd = dq; j = q * 256 + (int)(uq & 255u); }
        }
        jwin[tid] = j;
        atomicAdd(&counts[j], 1u);
    }
    __syncthreads();   // jwin ready; xls (A-tile) now dead -> reuse as nsu

    // Exact fp32 norms from the gathered winner; 8 lanes cooperate per row
    // (8 dims each). Noise read here: fully coalesced row-major.
    {
        const int rr2 = tid >> 3;   // row 0..63
        const int ql = tid & 7;     // 8-dim segment
        const int j = jwin[rr2];
        const float* cr = cb + (size_t)j * DD + ql * 8;
        const float4 c0 = *reinterpret_cast<const float4*>(cr);
        const float4 c1 = *reinterpret_cast<const float4*>(cr + 4);
        const float* nr = noise + (size_t)(nbase + rr2) * DD + ql * 8;
        const float4 nz0 = *reinterpret_cast<const float4*>(nr);
        const float4 nz1 = *reinterpret_cast<const float4*>(nr + 4);
        float sb = 0.0f, sn = 0.0f, df;
        df = xs[(ql * 8 + 0) * 65 + rr2] - c0.x; sb = fmaf(df, df, sb); sn = fmaf(nz0.x, nz0.x, sn);
        df = xs[(ql * 8 + 1) * 65 + rr2] - c0.y; sb = fmaf(df, df, sb); sn = fmaf(nz0.y, nz0.y, sn);
        df = xs[(ql * 8 + 2) * 65 + rr2] - c0.z; sb = fmaf(df, df, sb); sn = fmaf(nz0.z, nz0.z, sn);
        df = xs[(ql * 8 + 3) * 65 + rr2] - c0.w; sb = fmaf(df, df, sb); sn = fmaf(nz0.w, nz0.w, sn);
        df = xs[(ql * 8 + 4) * 65 + rr2] - c1.x; sb = fmaf(df, df, sb); sn = fmaf(nz1.x, nz1.x, sn);
        df = xs[(ql * 8 + 5) * 65 + rr2] - c1.y; sb = fmaf(df, df, sb); sn = fmaf(nz1.y, nz1.y, sn);
        df = xs[(ql * 8 + 6) * 65 + rr2] - c1.z; sb = fmaf(df, df, sb); sn = fmaf(nz1.z, nz1.z, sn);
        df = xs[(ql * 8 + 7) * 65 + rr2] - c1.w; sb = fmaf(df, df, sb); sn = fmaf(nz1.w, nz1.w, sn);
        sb += __shfl_xor(sb, 1); sb += __shfl_xor(sb, 2); sb += __shfl_xor(sb, 4);
        sn += __shfl_xor(sn, 1); sn += __shfl_xor(sn, 2); sn += __shfl_xor(sn, 4);
        if (ql == 0) sscale[rr2] = sqrtf(sb) / sqrtf(sn) + EPS_F;
        // park noise bf16 [r][d] (contiguous 16B store per thread)
        u16x8 pk;
        pk[0] = f2bf(nz0.x); pk[1] = f2bf(nz0.y); pk[2] = f2bf(nz0.z); pk[3] = f2bf(nz0.w);
        pk[4] = f2bf(nz1.x); pk[5] = f2bf(nz1.y); pk[6] = f2bf(nz1.z); pk[7] = f2bf(nz1.w);
        *reinterpret_cast<u16x8*>(&nsu[rr2 * 65 + ql * 8]) = pk;
    }
    __syncthreads();

    // quantized = x + scale*noise, NCHW-coalesced writes (256B segments).
#pragma unroll
    for (int i = 0; i < 8; ++i) {
        int idx = i * 512 + tid;  // = d*64 + r
        int d = idx >> 6, r = idx & 63;
        unsigned int nu = (unsigned int)nsu[r * 65 + d] << 16;
        out[(size_t)(b * DD + d) * HW + hwbase + r] =
            xs[d * 65 + r] + sscale[r] * __uint_as_float(nu);
    }
}

// ---------------------------------------------------------------------------
// Kernel 3: perplexity from the completed histogram. One block, 1024 threads.
// ---------------------------------------------------------------------------
__global__ __launch_bounds__(1024) void k_perp(const unsigned int* __restrict__ counts,
                                               float* __restrict__ out) {
    __shared__ float red[16];
    const int tid = threadIdx.x;
    const int lane = tid & 63;
    float p = (float)counts[tid] * (1.0f / (float)NN);
    float t = p * logf(p + PERP_EPS_F);
#pragma unroll
    for (int off = 32; off > 0; off >>= 1) t += __shfl_down(t, off);
    if (lane == 0) red[tid >> 6] = t;
    __syncthreads();
    if (tid == 0) {
        float s = 0.0f;
#pragma unroll
        for (int i = 0; i < 16; ++i) s += red[i];
        out[0] = expf(-s);
    }
}

// ---------------------------------------------------------------------------
extern "C" void kernel_launch(void* const* d_in, const int* in_sizes, int n_in,
                              void* d_out, int out_size, void* d_ws, size_t ws_size,
                              hipStream_t stream) {
    (void)in_sizes; (void)n_in; (void)out_size; (void)ws_size;
    const float* inp   = (const float*)d_in[0];   // (B,D,H,W)
    const float* cb    = (const float*)d_in[1];   // (K,D)
    const float* noise = (const float*)d_in[2];   // (N,D)
    float* out = (float*)d_out;                   // [NQ quantized][1 perplexity]

    char* ws = (char*)d_ws;
    float*          cnorm  = (float*)ws;                  // 4 KB
    unsigned int*   counts = (unsigned int*)(ws + 4096);  // 4 KB
    unsigned short* cbs    = (unsigned short*)(ws + 8192);// 128 KB (swizzled codebook)

    k_prep<<<16, 256, 0, stream>>>(cb, cbs, cnorm, counts);
    k_main<<<NBLK, 512, 0, stream>>>(inp, cbs, cb, cnorm, noise, counts, out);
    k_perp<<<1, 1024, 0, stream>>>(counts, out + NQ);
}

// Round 12
// 94.226 us; speedup vs baseline: 1.3368x; 1.3368x over previous
//
#include <hip/hip_runtime.h>
#include <hip/hip_bf16.h>
#include <math.h>

// Problem constants (from reference setup_inputs)
#define BB 32
#define DD 64
#define HH 32
#define WW 32
#define NN (BB * HH * WW)       // 32768 rows
#define KK 1024                 // codes
#define HW (HH * WW)            // 1024
#define NQ (BB * DD * HH * WW)  // 2097152 quantized elements
#define NBLK 512                // k_main grid (64 rows/block) -> 2 blocks/CU

#define EPS_F 1e-12f
#define PERP_EPS_F 1e-10f
#define DIST_BIAS 512.0f        // makes dist strictly positive -> uint-monotonic

typedef __attribute__((ext_vector_type(8))) __bf16 bf16x8;
typedef __attribute__((ext_vector_type(8))) unsigned short u16x8;
typedef __attribute__((ext_vector_type(4))) float f32x4;

// fp32 -> bf16 round-to-nearest-even, bit-level
static __device__ __forceinline__ unsigned short f2bf(float f) {
    union { float f; unsigned int u; } c;
    c.f = f;
    unsigned int r = c.u + 0x7FFFu + ((c.u >> 16) & 1u);
    return (unsigned short)(r >> 16);
}

// ---------------------------------------------------------------------------
// Kernel 1: codes fp32 -> bf16 pre-swizzled into MFMA B-frag order + norms +
// zero histogram. Swizzled layout: tile jt (16 codes), k-half f, MFMA lane
// l=(quad*16+col): element e at
//   cbs[((jt*2+f)*64 + l)*8 + e] == code[jt*16+col][f*32 + quad*8 + e]
// so the K-loop B-load is base + jt*2048B + lane*16B (fully coalesced).
// ---------------------------------------------------------------------------
__global__ __launch_bounds__(256) void k_prep(const float* __restrict__ cb,
                                              unsigned short* __restrict__ cbs,
                                              float* __restrict__ cnorm,
                                              unsigned int* __restrict__ counts) {
    const int gt = blockIdx.x * 256 + threadIdx.x;  // 0..4095
    const int j = gt >> 2;   // code 0..1023
    const int q = gt & 3;    // d-quarter 0..3
    const int jt = j >> 4;
    const int col = j & 15;
    const float4* src = reinterpret_cast<const float4*>(cb + (size_t)j * DD + q * 16);
    float4 v0 = src[0], v1 = src[1], v2 = src[2], v3 = src[3];
    float s = v0.x * v0.x + v0.y * v0.y + v0.z * v0.z + v0.w * v0.w
            + v1.x * v1.x + v1.y * v1.y + v1.z * v1.z + v1.w * v1.w
            + v2.x * v2.x + v2.y * v2.y + v2.z * v2.z + v2.w * v2.w
            + v3.x * v3.x + v3.y * v3.y + v3.z * v3.z + v3.w * v3.w;

#pragma unroll
    for (int i2 = 0; i2 < 2; ++i2) {
        const int quad_lin = q * 2 + i2;     // 0..7
        const int frag = quad_lin >> 2;      // k-half
        const int quad = quad_lin & 3;
        const int lane = quad * 16 + col;
        u16x8 pk;
        if (i2 == 0) {
            pk[0] = f2bf(v0.x); pk[1] = f2bf(v0.y); pk[2] = f2bf(v0.z); pk[3] = f2bf(v0.w);
            pk[4] = f2bf(v1.x); pk[5] = f2bf(v1.y); pk[6] = f2bf(v1.z); pk[7] = f2bf(v1.w);
        } else {
            pk[0] = f2bf(v2.x); pk[1] = f2bf(v2.y); pk[2] = f2bf(v2.z); pk[3] = f2bf(v2.w);
            pk[4] = f2bf(v3.x); pk[5] = f2bf(v3.y); pk[6] = f2bf(v3.z); pk[7] = f2bf(v3.w);
        }
        *reinterpret_cast<u16x8*>(cbs + ((size_t)(jt * 2 + frag) * 64 + lane) * 8) = pk;
    }

    s += __shfl_xor(s, 1);
    s += __shfl_xor(s, 2);
    if (q == 0) {
        cnorm[j] = s + DIST_BIAS;
        counts[j] = 0u;
    }
}

// ---------------------------------------------------------------------------
// Kernel 2 (fused): 512 blocks x 512 threads (8 waves), 64 rows/block.
// Waves = 2 row-halves (rh: 32 rows) x 4 code-quarters (w: 256 codes).
// NEW vs R10: per-block ROTATED tile order in the K-loop (lt = (jt+rot)&15)
// to de-phase the chip-wide sweep of the shared codebook lines (L2 same-line
// contention theory). Min-reduction is order-agnostic -> bit-identical result.
// Argmin packed u32: (bits(dist+512) & ~255) | local_code_idx.
// Epilogue: exact fp32 norms, noise injection (bf16-parked in retired A-tile
// scratch), NCHW writes, histogram. No device fences.
// ---------------------------------------------------------------------------
__global__ __launch_bounds__(512) void k_main(const float* __restrict__ inp,
                                              const unsigned short* __restrict__ cbs,
                                              const float* __restrict__ cb,
                                              const float* __restrict__ cnorm,
                                              const float* __restrict__ noise,
                                              unsigned int* __restrict__ counts,
                                              float* __restrict__ out) {
    __shared__ float xs[64 * 65];                          // fp32 x, [d][r] stride 65
    __shared__ __align__(16) unsigned short scratch[64 * 72];  // A-tile; later bf16 noise [r][d]@65
    __shared__ unsigned int mg[64 * 4];                    // winner per [row][quarter]
    __shared__ int jwin[64];
    __shared__ float sscale[64];

    unsigned short* xls = scratch;            // bf16 A-tile [r][d], stride 72
    unsigned short* nsu = scratch;            // later: bf16 noise [r][d], stride 65

    const int tid = threadIdx.x;
    const int nbase = blockIdx.x * 64;
    const int b = nbase >> 10;        // 64 | 1024: no batch/HW crossing
    const int hwbase = nbase & 1023;
    const float* xg = inp + (size_t)b * (DD * HW) + hwbase;

    const int lane = tid & 63;
    const int wid = tid >> 6;      // 0..7
    const int w = wid & 3;         // code quarter
    const int rh = wid >> 2;       // row half
    const int rbase = rh * 32;
    const int col = lane & 15;
    const int quad = lane >> 4;

    // Per-block sweep rotation (odd multiplier spreads starting tiles).
    const int rot = (blockIdx.x * 5) & 15;

    // Stage x fp32: global [d][hw] -> coalesced (256B segments); LDS stride 65.
#pragma unroll
    for (int i = 0; i < 8; ++i) {
        int idx = i * 512 + tid;  // = d*64 + r
        int d = idx >> 6, r = idx & 63;
        xs[d * 65 + r] = xg[d * HW + r];
    }
    __syncthreads();

    // Build bf16 A-tile [r][d]: thread -> (row rr=tid>>3, octet sg=tid&7).
    {
        const int rr = tid >> 3;    // 0..63
        const int sg = tid & 7;     // 8 dims each
        u16x8 pk;
#pragma unroll
        for (int j2 = 0; j2 < 8; ++j2)
            pk[j2] = f2bf(xs[(sg * 8 + j2) * 65 + rr]);
        *reinterpret_cast<u16x8*>(&xls[rr * 72 + sg * 8]) = pk;
    }
    __syncthreads();

    // A fragments: A[m=lane&15][k=quad*8+j]; 2 row-tiles x 2 k-halves.
    const bf16x8 a00 = *reinterpret_cast<const bf16x8*>(&xls[(rbase + col) * 72 + quad * 8]);
    const bf16x8 a01 = *reinterpret_cast<const bf16x8*>(&xls[(rbase + col) * 72 + 32 + quad * 8]);
    const bf16x8 a10 = *reinterpret_cast<const bf16x8*>(&xls[(rbase + 16 + col) * 72 + quad * 8]);
    const bf16x8 a11 = *reinterpret_cast<const bf16x8*>(&xls[(rbase + 16 + col) * 72 + 32 + quad * 8]);

    unsigned int minu[8];
#pragma unroll
    for (int s = 0; s < 8; ++s) minu[s] = 0xFFFFFFFFu;

    // Swizzled B base for this wave's quarter: tile lt at + lt*1024 elems,
    // lane's 16B at + lane*8; k-half 1 at +512. Fully coalesced.
    const unsigned short* bp = cbs + (size_t)w * 16 * 1024 + lane * 8;
    const float* cnp = cnorm + w * 256 + col;

    // Software pipeline: preload groups 0 and 1 (rotated tiles).
    bf16x8 bb[2][4];
#pragma unroll
    for (int pg = 0; pg < 2; ++pg) {
#pragma unroll
        for (int t2 = 0; t2 < 2; ++t2) {
            const int lt = ((pg * 2 + t2) + rot) & 15;
            const size_t off = (size_t)lt * 1024;
            bb[pg][t2 * 2]     = *reinterpret_cast<const bf16x8*>(bp + off);
            bb[pg][t2 * 2 + 1] = *reinterpret_cast<const bf16x8*>(bp + off + 512);
        }
    }

#pragma unroll
    for (int g = 0; g < 8; ++g) {
        const int cb_ = g & 1;
#pragma unroll
        for (int t2 = 0; t2 < 2; ++t2) {
            const int lt = ((g * 2 + t2) + rot) & 15;   // rotated logical tile
            f32x4 acc0 = {0.f, 0.f, 0.f, 0.f};
            f32x4 acc1 = {0.f, 0.f, 0.f, 0.f};
            acc0 = __builtin_amdgcn_mfma_f32_16x16x32_bf16(a00, bb[cb_][t2 * 2], acc0, 0, 0, 0);
            acc0 = __builtin_amdgcn_mfma_f32_16x16x32_bf16(a01, bb[cb_][t2 * 2 + 1], acc0, 0, 0, 0);
            acc1 = __builtin_amdgcn_mfma_f32_16x16x32_bf16(a10, bb[cb_][t2 * 2], acc1, 0, 0, 0);
            acc1 = __builtin_amdgcn_mfma_f32_16x16x32_bf16(a11, bb[cb_][t2 * 2 + 1], acc1, 0, 0, 0);
            const float cnt = cnp[lt * 16];
            const unsigned int jc = (unsigned int)(lt * 16 + col);  // 8-bit local idx
#pragma unroll
            for (int r = 0; r < 4; ++r) {
                float d0 = fmaf(-2.0f, acc0[r], cnt);
                unsigned int u0 = (__float_as_uint(d0) & ~255u) | jc;
                minu[r] = minu[r] < u0 ? minu[r] : u0;
                float d1 = fmaf(-2.0f, acc1[r], cnt);
                unsigned int u1 = (__float_as_uint(d1) & ~255u) | jc;
                minu[4 + r] = minu[4 + r] < u1 ? minu[4 + r] : u1;
            }
        }
        // Prefetch group g+2 (rotated) into the buffer just consumed.
        if (g < 6) {
#pragma unroll
            for (int t2 = 0; t2 < 2; ++t2) {
                const int lt = (((g + 2) * 2 + t2) + rot) & 15;
                const size_t off = (size_t)lt * 1024;
                bb[cb_][t2 * 2]     = *reinterpret_cast<const bf16x8*>(bp + off);
                bb[cb_][t2 * 2 + 1] = *reinterpret_cast<const bf16x8*>(bp + off + 512);
            }
        }
    }

    // 16-col butterfly per quad; index rides in the low bits -> lowest-index tie.
#pragma unroll
    for (int s = 0; s < 8; ++s) {
        unsigned int v = minu[s];
#pragma unroll
        for (int off = 1; off < 16; off <<= 1) {
            unsigned int ov = (unsigned int)__shfl_xor((int)v, off);
            v = v < ov ? v : ov;
        }
        if (col == 0) {
            const int rloc = rbase + (s >> 2) * 16 + quad * 4 + (s & 3);
            mg[rloc * 4 + w] = v;
        }
    }
    __syncthreads();

    // Merge the 4 code-quarters per row; strict '<' keeps lowest quarter on tie.
    if (tid < 64) {
        unsigned int best = mg[tid * 4 + 0];
        unsigned int bestd = best & ~255u;
        int j = (int)(best & 255u);
#pragma unroll
        for (int q = 1; q < 4; ++q) {
            unsigned int uq = mg[tid * 4 + q];
            unsigned int dq = uq & ~255u;
            if (dq < bestd) { bestd = dq; j = q * 256 + (int)(uq & 255u); }
        }
        jwin[tid] = j;
        atomicAdd(&counts[j], 1u);
    }
    __syncthreads();   // jwin ready; xls (A-tile) now dead -> reuse as nsu

    // Exact fp32 norms from the gathered winner; 8 lanes cooperate per row
    // (8 dims each). Noise read here: fully coalesced row-major.
    {
        const int rr2 = tid >> 3;   // row 0..63
        const int ql = tid & 7;     // 8-dim segment
        const int j = jwin[rr2];
        const float* cr = cb + (size_t)j * DD + ql * 8;
        const float4 c0 = *reinterpret_cast<const float4*>(cr);
        const float4 c1 = *reinterpret_cast<const float4*>(cr + 4);
        const float* nr = noise + (size_t)(nbase + rr2) * DD + ql * 8;
        const float4 nz0 = *reinterpret_cast<const float4*>(nr);
        const float4 nz1 = *reinterpret_cast<const float4*>(nr + 4);
        float sb = 0.0f, sn = 0.0f, df;
        df = xs[(ql * 8 + 0) * 65 + rr2] - c0.x; sb = fmaf(df, df, sb); sn = fmaf(nz0.x, nz0.x, sn);
        df = xs[(ql * 8 + 1) * 65 + rr2] - c0.y; sb = fmaf(df, df, sb); sn = fmaf(nz0.y, nz0.y, sn);
        df = xs[(ql * 8 + 2) * 65 + rr2] - c0.z; sb = fmaf(df, df, sb); sn = fmaf(nz0.z, nz0.z, sn);
        df = xs[(ql * 8 + 3) * 65 + rr2] - c0.w; sb = fmaf(df, df, sb); sn = fmaf(nz0.w, nz0.w, sn);
        df = xs[(ql * 8 + 4) * 65 + rr2] - c1.x; sb = fmaf(df, df, sb); sn = fmaf(nz1.x, nz1.x, sn);
        df = xs[(ql * 8 + 5) * 65 + rr2] - c1.y; sb = fmaf(df, df, sb); sn = fmaf(nz1.y, nz1.y, sn);
        df = xs[(ql * 8 + 6) * 65 + rr2] - c1.z; sb = fmaf(df, df, sb); sn = fmaf(nz1.z, nz1.z, sn);
        df = xs[(ql * 8 + 7) * 65 + rr2] - c1.w; sb = fmaf(df, df, sb); sn = fmaf(nz1.w, nz1.w, sn);
        sb += __shfl_xor(sb, 1); sb += __shfl_xor(sb, 2); sb += __shfl_xor(sb, 4);
        sn += __shfl_xor(sn, 1); sn += __shfl_xor(sn, 2); sn += __shfl_xor(sn, 4);
        if (ql == 0) sscale[rr2] = sqrtf(sb) / sqrtf(sn) + EPS_F;
        // park noise bf16 [r][d] (contiguous 16B store per thread)
        u16x8 pk;
        pk[0] = f2bf(nz0.x); pk[1] = f2bf(nz0.y); pk[2] = f2bf(nz0.z); pk[3] = f2bf(nz0.w);
        pk[4] = f2bf(nz1.x); pk[5] = f2bf(nz1.y); pk[6] = f2bf(nz1.z); pk[7] = f2bf(nz1.w);
        *reinterpret_cast<u16x8*>(&nsu[rr2 * 65 + ql * 8]) = pk;
    }
    __syncthreads();

    // quantized = x + scale*noise, NCHW-coalesced writes (256B segments).
#pragma unroll
    for (int i = 0; i < 8; ++i) {
        int idx = i * 512 + tid;  // = d*64 + r
        int d = idx >> 6, r = idx & 63;
        unsigned int nu = (unsigned int)nsu[r * 65 + d] << 16;
        out[(size_t)(b * DD + d) * HW + hwbase + r] =
            xs[d * 65 + r] + sscale[r] * __uint_as_float(nu);
    }
}

// ---------------------------------------------------------------------------
// Kernel 3: perplexity from the completed histogram. One block, 1024 threads.
// ---------------------------------------------------------------------------
__global__ __launch_bounds__(1024) void k_perp(const unsigned int* __restrict__ counts,
                                               float* __restrict__ out) {
    __shared__ float red[16];
    const int tid = threadIdx.x;
    const int lane = tid & 63;
    float p = (float)counts[tid] * (1.0f / (float)NN);
    float t = p * logf(p + PERP_EPS_F);
#pragma unroll
    for (int off = 32; off > 0; off >>= 1) t += __shfl_down(t, off);
    if (lane == 0) red[tid >> 6] = t;
    __syncthreads();
    if (tid == 0) {
        float s = 0.0f;
#pragma unroll
        for (int i = 0; i < 16; ++i) s += red[i];
        out[0] = expf(-s);
    }
}

// ---------------------------------------------------------------------------
extern "C" void kernel_launch(void* const* d_in, const int* in_sizes, int n_in,
                              void* d_out, int out_size, void* d_ws, size_t ws_size,
                              hipStream_t stream) {
    (void)in_sizes; (void)n_in; (void)out_size; (void)ws_size;
    const float* inp   = (const float*)d_in[0];   // (B,D,H,W)
    const float* cb    = (const float*)d_in[1];   // (K,D)
    const float* noise = (const float*)d_in[2];   // (N,D)
    float* out = (float*)d_out;                   // [NQ quantized][1 perplexity]

    char* ws = (char*)d_ws;
    float*          cnorm  = (float*)ws;                  // 4 KB
    unsigned int*   counts = (unsigned int*)(ws + 4096);  // 4 KB
    unsigned short* cbs    = (unsigned short*)(ws + 8192);// 128 KB (swizzled codebook)

    k_prep<<<16, 256, 0, stream>>>(cb, cbs, cnorm, counts);
    k_main<<<NBLK, 512, 0, stream>>>(inp, cbs, cb, cnorm, noise, counts, out);
    k_perp<<<1, 1024, 0, stream>>>(counts, out + NQ);
}

// Round 13
// 92.093 us; speedup vs baseline: 1.3678x; 1.0232x over previous
//
#include <hip/hip_runtime.h>
#include <hip/hip_bf16.h>
#include <math.h>

// Problem constants (from reference setup_inputs)
#define BB 32
#define DD 64
#define HH 32
#define WW 32
#define NN (BB * HH * WW)       // 32768 rows
#define KK 1024                 // codes
#define HW (HH * WW)            // 1024
#define NQ (BB * DD * HH * WW)  // 2097152 quantized elements
#define NBLK 512                // k_main grid (64 rows/block) -> 2 blocks/CU

#define EPS_F 1e-12f
#define PERP_EPS_F 1e-10f
#define DIST_BIAS 512.0f        // makes dist strictly positive -> uint-monotonic

typedef __attribute__((ext_vector_type(8))) __bf16 bf16x8;
typedef __attribute__((ext_vector_type(8))) unsigned short u16x8;
typedef __attribute__((ext_vector_type(4))) float f32x4;

// fp32 -> bf16 round-to-nearest-even, bit-level
static __device__ __forceinline__ unsigned short f2bf(float f) {
    union { float f; unsigned int u; } c;
    c.f = f;
    unsigned int r = c.u + 0x7FFFu + ((c.u >> 16) & 1u);
    return (unsigned short)(r >> 16);
}

// ---------------------------------------------------------------------------
// Kernel 1: codes fp32 -> bf16 pre-swizzled into MFMA B-frag order + norms +
// zero histogram. Swizzled layout: tile jt (16 codes), k-half f, MFMA lane
// l=(quad*16+col): element e at
//   cbs[((jt*2+f)*64 + l)*8 + e] == code[jt*16+col][f*32 + quad*8 + e]
// so the K-loop B-load is base + jt*2048B + lane*16B (fully coalesced).
// ---------------------------------------------------------------------------
__global__ __launch_bounds__(256) void k_prep(const float* __restrict__ cb,
                                              unsigned short* __restrict__ cbs,
                                              float* __restrict__ cnorm,
                                              unsigned int* __restrict__ counts) {
    const int gt = blockIdx.x * 256 + threadIdx.x;  // 0..4095
    const int j = gt >> 2;   // code 0..1023
    const int q = gt & 3;    // d-quarter 0..3
    const int jt = j >> 4;
    const int col = j & 15;
    const float4* src = reinterpret_cast<const float4*>(cb + (size_t)j * DD + q * 16);
    float4 v0 = src[0], v1 = src[1], v2 = src[2], v3 = src[3];
    float s = v0.x * v0.x + v0.y * v0.y + v0.z * v0.z + v0.w * v0.w
            + v1.x * v1.x + v1.y * v1.y + v1.z * v1.z + v1.w * v1.w
            + v2.x * v2.x + v2.y * v2.y + v2.z * v2.z + v2.w * v2.w
            + v3.x * v3.x + v3.y * v3.y + v3.z * v3.z + v3.w * v3.w;

#pragma unroll
    for (int i2 = 0; i2 < 2; ++i2) {
        const int quad_lin = q * 2 + i2;     // 0..7
        const int frag = quad_lin >> 2;      // k-half
        const int quad = quad_lin & 3;
        const int lane = quad * 16 + col;
        u16x8 pk;
        if (i2 == 0) {
            pk[0] = f2bf(v0.x); pk[1] = f2bf(v0.y); pk[2] = f2bf(v0.z); pk[3] = f2bf(v0.w);
            pk[4] = f2bf(v1.x); pk[5] = f2bf(v1.y); pk[6] = f2bf(v1.z); pk[7] = f2bf(v1.w);
        } else {
            pk[0] = f2bf(v2.x); pk[1] = f2bf(v2.y); pk[2] = f2bf(v2.z); pk[3] = f2bf(v2.w);
            pk[4] = f2bf(v3.x); pk[5] = f2bf(v3.y); pk[6] = f2bf(v3.z); pk[7] = f2bf(v3.w);
        }
        *reinterpret_cast<u16x8*>(cbs + ((size_t)(jt * 2 + frag) * 64 + lane) * 8) = pk;
    }

    s += __shfl_xor(s, 1);
    s += __shfl_xor(s, 2);
    if (q == 0) {
        cnorm[j] = s + DIST_BIAS;
        counts[j] = 0u;
    }
}

// ---------------------------------------------------------------------------
// Kernel 2 (fused): 512 blocks x 512 threads (8 waves), 64 rows/block.
// Waves = 2 row-halves (rh: 32 rows) x 4 code-quarters (w: 256 codes).
// NEW vs R12: (1) B group-0/1 loads issued BEFORE x-staging (L2 latency
// overlaps HBM staging); (2) noise prefetched to regs during staging;
// (3) NO winner gather -- norm recovered from the packed winner distance:
// ||x-c*||^2 = dist_packed + ||x||^2, with ||x||^2 computed in the convert
// phase. Tail after the K-loop is pure register/LDS work.
// Argmin packed u32: (bits(dist+512) & ~255) | local_code_idx.
// ---------------------------------------------------------------------------
__global__ __launch_bounds__(512) void k_main(const float* __restrict__ inp,
                                              const unsigned short* __restrict__ cbs,
                                              const float* __restrict__ cnorm,
                                              const float* __restrict__ noise,
                                              unsigned int* __restrict__ counts,
                                              float* __restrict__ out) {
    __shared__ float xs[64 * 65];                          // fp32 x, [d][r] stride 65
    __shared__ __align__(16) unsigned short scratch[64 * 72];  // A-tile; later bf16 noise [r][d]@65
    __shared__ unsigned int mg[64 * 4];                    // winner per [row][quarter]
    __shared__ float dw[64];                               // winner quantized dist per row
    __shared__ float sxs[64];                              // ||x||^2 per row
    __shared__ float sscale[64];

    unsigned short* xls = scratch;            // bf16 A-tile [r][d], stride 72
    unsigned short* nsu = scratch;            // later: bf16 noise [r][d], stride 65

    const int tid = threadIdx.x;
    const int nbase = blockIdx.x * 64;
    const int b = nbase >> 10;        // 64 | 1024: no batch/HW crossing
    const int hwbase = nbase & 1023;
    const float* xg = inp + (size_t)b * (DD * HW) + hwbase;

    const int lane = tid & 63;
    const int wid = tid >> 6;      // 0..7
    const int w = wid & 3;         // code quarter
    const int rh = wid >> 2;       // row half
    const int rbase = rh * 32;
    const int col = lane & 15;
    const int quad = lane >> 4;

    // Swizzled B base for this wave's quarter.
    const unsigned short* bp = cbs + (size_t)w * 16 * 1024 + lane * 8;
    const float* cnp = cnorm + w * 256 + col;

    // (1) EARLY B prefetch: groups 0 and 1 issued before anything else --
    // their L2 latency overlaps the HBM staging below.
    bf16x8 bb[2][4];
#pragma unroll
    for (int pg = 0; pg < 2; ++pg) {
#pragma unroll
        for (int t2 = 0; t2 < 2; ++t2) {
            const size_t off = (size_t)(pg * 2 + t2) * 1024;
            bb[pg][t2 * 2]     = *reinterpret_cast<const bf16x8*>(bp + off);
            bb[pg][t2 * 2 + 1] = *reinterpret_cast<const bf16x8*>(bp + off + 512);
        }
    }

    // Stage x fp32: global [d][hw] -> coalesced (256B segments); LDS stride 65.
#pragma unroll
    for (int i = 0; i < 8; ++i) {
        int idx = i * 512 + tid;  // = d*64 + r
        int d = idx >> 6, r = idx & 63;
        xs[d * 65 + r] = xg[d * HW + r];
    }

    // (2) Noise prefetch to regs (consumed only in the tail; huge slack).
    const int rrn = tid >> 3;    // row 0..63
    const int qln = tid & 7;     // 8-dim segment
    const float* nr = noise + (size_t)(nbase + rrn) * DD + qln * 8;
    const float4 nz0 = *reinterpret_cast<const float4*>(nr);
    const float4 nz1 = *reinterpret_cast<const float4*>(nr + 4);

    __syncthreads();

    // Convert phase + ||x||^2: thread -> (row rr=tid>>3, octet sg=tid&7).
    {
        u16x8 pk;
        float sx = 0.0f;
#pragma unroll
        for (int j2 = 0; j2 < 8; ++j2) {
            float v = xs[(qln * 8 + j2) * 65 + rrn];
            pk[j2] = f2bf(v);
            sx = fmaf(v, v, sx);
        }
        *reinterpret_cast<u16x8*>(&xls[rrn * 72 + qln * 8]) = pk;
        sx += __shfl_xor(sx, 1); sx += __shfl_xor(sx, 2); sx += __shfl_xor(sx, 4);
        if (qln == 0) sxs[rrn] = sx;
    }
    __syncthreads();

    // A fragments: A[m=lane&15][k=quad*8+j]; 2 row-tiles x 2 k-halves.
    const bf16x8 a00 = *reinterpret_cast<const bf16x8*>(&xls[(rbase + col) * 72 + quad * 8]);
    const bf16x8 a01 = *reinterpret_cast<const bf16x8*>(&xls[(rbase + col) * 72 + 32 + quad * 8]);
    const bf16x8 a10 = *reinterpret_cast<const bf16x8*>(&xls[(rbase + 16 + col) * 72 + quad * 8]);
    const bf16x8 a11 = *reinterpret_cast<const bf16x8*>(&xls[(rbase + 16 + col) * 72 + 32 + quad * 8]);

    unsigned int minu[8];
#pragma unroll
    for (int s = 0; s < 8; ++s) minu[s] = 0xFFFFFFFFu;

#pragma unroll
    for (int g = 0; g < 8; ++g) {
        const int cb_ = g & 1;
#pragma unroll
        for (int t2 = 0; t2 < 2; ++t2) {
            const int jt = g * 2 + t2;
            f32x4 acc0 = {0.f, 0.f, 0.f, 0.f};
            f32x4 acc1 = {0.f, 0.f, 0.f, 0.f};
            acc0 = __builtin_amdgcn_mfma_f32_16x16x32_bf16(a00, bb[cb_][t2 * 2], acc0, 0, 0, 0);
            acc0 = __builtin_amdgcn_mfma_f32_16x16x32_bf16(a01, bb[cb_][t2 * 2 + 1], acc0, 0, 0, 0);
            acc1 = __builtin_amdgcn_mfma_f32_16x16x32_bf16(a10, bb[cb_][t2 * 2], acc1, 0, 0, 0);
            acc1 = __builtin_amdgcn_mfma_f32_16x16x32_bf16(a11, bb[cb_][t2 * 2 + 1], acc1, 0, 0, 0);
            const float cnt = cnp[jt * 16];
            const unsigned int jc = (unsigned int)(jt * 16 + col);  // 8-bit local idx
#pragma unroll
            for (int r = 0; r < 4; ++r) {
                float d0 = fmaf(-2.0f, acc0[r], cnt);
                unsigned int u0 = (__float_as_uint(d0) & ~255u) | jc;
                minu[r] = minu[r] < u0 ? minu[r] : u0;
                float d1 = fmaf(-2.0f, acc1[r], cnt);
                unsigned int u1 = (__float_as_uint(d1) & ~255u) | jc;
                minu[4 + r] = minu[4 + r] < u1 ? minu[4 + r] : u1;
            }
        }
        // Prefetch group g+2 into the buffer just consumed (2-group lookahead).
        if (g < 6) {
#pragma unroll
            for (int t2 = 0; t2 < 2; ++t2) {
                const size_t off = (size_t)((g + 2) * 2 + t2) * 1024;
                bb[cb_][t2 * 2]     = *reinterpret_cast<const bf16x8*>(bp + off);
                bb[cb_][t2 * 2 + 1] = *reinterpret_cast<const bf16x8*>(bp + off + 512);
            }
        }
    }

    // 16-col butterfly per quad; index rides in the low bits -> lowest-index tie.
#pragma unroll
    for (int s = 0; s < 8; ++s) {
        unsigned int v = minu[s];
#pragma unroll
        for (int off = 1; off < 16; off <<= 1) {
            unsigned int ov = (unsigned int)__shfl_xor((int)v, off);
            v = v < ov ? v : ov;
        }
        if (col == 0) {
            const int rloc = rbase + (s >> 2) * 16 + quad * 4 + (s & 3);
            mg[rloc * 4 + w] = v;
        }
    }
    __syncthreads();

    // Merge the 4 code-quarters per row; strict '<' keeps lowest quarter on tie.
    // (3) Winner distance recovered from the packed value -- no gather.
    if (tid < 64) {
        unsigned int best = mg[tid * 4 + 0];
        unsigned int bestd = best & ~255u;
        int j = (int)(best & 255u);
#pragma unroll
        for (int q = 1; q < 4; ++q) {
            unsigned int uq = mg[tid * 4 + q];
            unsigned int dq = uq & ~255u;
            if (dq < bestd) { bestd = dq; j = q * 256 + (int)(uq & 255u); }
        }
        dw[tid] = __uint_as_float(bestd) - DIST_BIAS;   // ||c||^2 - 2x.c (quantized)
        atomicAdd(&counts[j], 1u);
    }
    __syncthreads();   // dw/sxs ready; xls (A-tile) dead -> reuse as nsu

    // Tail: ||noise||^2 from regs, scale from packed dist + ||x||^2.
    {
        float sn = 0.0f;
        sn = fmaf(nz0.x, nz0.x, sn); sn = fmaf(nz0.y, nz0.y, sn);
        sn = fmaf(nz0.z, nz0.z, sn); sn = fmaf(nz0.w, nz0.w, sn);
        sn = fmaf(nz1.x, nz1.x, sn); sn = fmaf(nz1.y, nz1.y, sn);
        sn = fmaf(nz1.z, nz1.z, sn); sn = fmaf(nz1.w, nz1.w, sn);
        sn += __shfl_xor(sn, 1); sn += __shfl_xor(sn, 2); sn += __shfl_xor(sn, 4);
        if (qln == 0) {
            float nb2 = fmaxf(dw[rrn] + sxs[rrn], 0.0f);   // ||x - c*||^2
            sscale[rrn] = sqrtf(nb2) / sqrtf(sn) + EPS_F;
        }
        // park noise bf16 [r][d] (contiguous 16B store per thread)
        u16x8 pk;
        pk[0] = f2bf(nz0.x); pk[1] = f2bf(nz0.y); pk[2] = f2bf(nz0.z); pk[3] = f2bf(nz0.w);
        pk[4] = f2bf(nz1.x); pk[5] = f2bf(nz1.y); pk[6] = f2bf(nz1.z); pk[7] = f2bf(nz1.w);
        *reinterpret_cast<u16x8*>(&nsu[rrn * 65 + qln * 8]) = pk;
    }
    __syncthreads();

    // quantized = x + scale*noise, NCHW-coalesced writes (256B segments).
#pragma unroll
    for (int i = 0; i < 8; ++i) {
        int idx = i * 512 + tid;  // = d*64 + r
        int d = idx >> 6, r = idx & 63;
        unsigned int nu = (unsigned int)nsu[r * 65 + d] << 16;
        out[(size_t)(b * DD + d) * HW + hwbase + r] =
            xs[d * 65 + r] + sscale[r] * __uint_as_float(nu);
    }
}

// ---------------------------------------------------------------------------
// Kernel 3: perplexity from the completed histogram. One block, 1024 threads.
// ---------------------------------------------------------------------------
__global__ __launch_bounds__(1024) void k_perp(const unsigned int* __restrict__ counts,
                                               float* __restrict__ out) {
    __shared__ float red[16];
    const int tid = threadIdx.x;
    const int lane = tid & 63;
    float p = (float)counts[tid] * (1.0f / (float)NN);
    float t = p * logf(p + PERP_EPS_F);
#pragma unroll
    for (int off = 32; off > 0; off >>= 1) t += __shfl_down(t, off);
    if (lane == 0) red[tid >> 6] = t;
    __syncthreads();
    if (tid == 0) {
        float s = 0.0f;
#pragma unroll
        for (int i = 0; i < 16; ++i) s += red[i];
        out[0] = expf(-s);
    }
}

// ---------------------------------------------------------------------------
extern "C" void kernel_launch(void* const* d_in, const int* in_sizes, int n_in,
                              void* d_out, int out_size, void* d_ws, size_t ws_size,
                              hipStream_t stream) {
    (void)in_sizes; (void)n_in; (void)out_size; (void)ws_size;
    const float* inp   = (const float*)d_in[0];   // (B,D,H,W)
    const float* cb    = (const float*)d_in[1];   // (K,D)
    const float* noise = (const float*)d_in[2];   // (N,D)
    float* out = (float*)d_out;                   // [NQ quantized][1 perplexity]

    char* ws = (char*)d_ws;
    float*          cnorm  = (float*)ws;                  // 4 KB
    unsigned int*   counts = (unsigned int*)(ws + 4096);  // 4 KB
    unsigned short* cbs    = (unsigned short*)(ws + 8192);// 128 KB (swizzled codebook)

    k_prep<<<16, 256, 0, stream>>>(cb, cbs, cnorm, counts);
    k_main<<<NBLK, 512, 0, stream>>>(inp, cbs, cnorm, noise, counts, out);
    k_perp<<<1, 1024, 0, stream>>>(counts, out + NQ);
}